// Round 3
// baseline (281.591 us; speedup 1.0000x reference)
//
#include <hip/hip_runtime.h>

// ---------- helpers ----------
__device__ __forceinline__ float2 cmul(float2 a, float2 b){
    return make_float2(a.x*b.x - a.y*b.y, a.x*b.y + a.y*b.x);
}
__device__ __forceinline__ float2 cadd(float2 a, float2 b){
    return make_float2(a.x + b.x, a.y + b.y);
}
__device__ __forceinline__ unsigned short f2h(float f){
    _Float16 h = (_Float16)f;                    // v_cvt_f16_f32, round-nearest
    return __builtin_bit_cast(unsigned short, h);
}

typedef _Float16 f16x8 __attribute__((ext_vector_type(8)));
typedef float    f32x4 __attribute__((ext_vector_type(4)));

// ---------- K1: build per-layer 256x256 effective operators ----------
// NOTE: the reference's einsum('st,bpsq->bptq') applies U^T, so the effective
// per-qubit operator is RZ^T * RY^T * RX^T = RZ * RY(-theta) * RX
// (RX, RZ symmetric; RY transpose flips its sine sign).
// U_l[k][c] = T[P(k)][c],  T = G7 (x) ... (x) G0, qubit i on bit (7-i).
__global__ void k_build_layers(const float* __restrict__ qw, float2* __restrict__ U){
    __shared__ float2 G[8][2][2];
    int l = blockIdx.y, k = blockIdx.x, c = threadIdx.x;
    if (c < 8){
        int i = c;
        float t0 = 0.5f*qw[l*24 + i*3 + 0];
        float t1 = 0.5f*qw[l*24 + i*3 + 1];
        float t2 = 0.5f*qw[l*24 + i*3 + 2];
        float c1,s1,c2,s2,c3,s3;
        sincosf(t0,&s1,&c1); sincosf(t1,&s2,&c2); sincosf(t2,&s3,&c3);
        // RX = [[(c1,0),(0,-s1)],[(0,-s1),(c1,0)]]  (symmetric)
        float2 RX[2][2] = {{{c1,0.f},{0.f,-s1}},{{0.f,-s1},{c1,0.f}}};
        // RY^T = [[(c2,0),(s2,0)],[(-s2,0),(c2,0)]]   <-- transposed!
        float2 RY[2][2] = {{{c2,0.f},{s2,0.f}},{{-s2,0.f},{c2,0.f}}};
        float2 M[2][2];
        #pragma unroll
        for (int r=0;r<2;++r)
            #pragma unroll
            for (int cc=0;cc<2;++cc)
                M[r][cc] = cadd(cmul(RY[r][0],RX[0][cc]), cmul(RY[r][1],RX[1][cc]));
        float2 e  = {c3,-s3};   // exp(-i t2)
        float2 ec = {c3, s3};
        G[i][0][0]=cmul(e, M[0][0]); G[i][0][1]=cmul(e, M[0][1]);
        G[i][1][0]=cmul(ec,M[1][0]); G[i][1][1]=cmul(ec,M[1][1]);
    }
    __syncthreads();
    // P(k): apply CNOT list in reverse order (each is an involution)
    int r = k;
    for (int i=6;i>=0;--i)
        for (int j=7;j>i;--j)
            if ((r >> (7-i)) & 1) r ^= 1 << (7-j);
    float2 p = {1.f, 0.f};
    #pragma unroll
    for (int i=0;i<8;++i)
        p = cmul(p, G[i][(r>>(7-i))&1][(c>>(7-i))&1]);
    U[l*65536 + k*256 + c] = p;
}

// ---------- K2: complex matmul C = A*B (256x256) ----------
__global__ void k_cmm(const float2* __restrict__ A, const float2* __restrict__ B,
                      float2* __restrict__ C){
    __shared__ float2 Ar[2][256];
    int r0 = blockIdx.x*2, c = threadIdx.x;
    Ar[0][c] = A[r0*256 + c];
    Ar[1][c] = A[(r0+1)*256 + c];
    __syncthreads();
    float2 a0 = {0.f,0.f}, a1 = {0.f,0.f};
    #pragma unroll 8
    for (int m=0;m<256;++m){
        float2 b = B[m*256 + c];
        a0 = cadd(a0, cmul(Ar[0][m], b));
        a1 = cadd(a1, cmul(Ar[1][m], b));
    }
    C[r0*256 + c] = a0;
    C[(r0+1)*256 + c] = a1;
}

// ---------- K3: complex matmul -> fp16 W matrix (512x256: [Re; Im]) ----------
__global__ void k_cmm_f16(const float2* __restrict__ A, const float2* __restrict__ B,
                          unsigned short* __restrict__ W){
    __shared__ float2 Ar[2][256];
    int r0 = blockIdx.x*2, c = threadIdx.x;
    Ar[0][c] = A[r0*256 + c];
    Ar[1][c] = A[(r0+1)*256 + c];
    __syncthreads();
    float2 a0 = {0.f,0.f}, a1 = {0.f,0.f};
    #pragma unroll 8
    for (int m=0;m<256;++m){
        float2 b = B[m*256 + c];
        a0 = cadd(a0, cmul(Ar[0][m], b));
        a1 = cadd(a1, cmul(Ar[1][m], b));
    }
    W[r0*256 + c]       = f2h(a0.x);
    W[(r0+256)*256 + c] = f2h(a0.y);
    W[(r0+1)*256 + c]       = f2h(a1.x);
    W[(r0+257)*256 + c] = f2h(a1.y);
}

// ---------- K4: fp32 front MLP: x -> pre (65536 x 8) ----------
__global__ __launch_bounds__(256) void k_mlp_front(
    const float* __restrict__ x,
    const float* __restrict__ W1, const float* __restrict__ b1, const float* __restrict__ g1,
    const float* __restrict__ bt1, const float* __restrict__ m1, const float* __restrict__ v1,
    const float* __restrict__ W2, const float* __restrict__ b2, const float* __restrict__ g2,
    const float* __restrict__ bt2, const float* __restrict__ m2, const float* __restrict__ v2,
    const float* __restrict__ W3, const float* __restrict__ b3,
    float* __restrict__ pre)
{
    __shared__ float sW1[128*16];
    __shared__ float sA1[128], sB1[128];
    __shared__ float sW2[64*128];
    __shared__ float sA2[64], sB2[64];
    __shared__ float sW3[8*64];
    __shared__ float sb3[8];
    int tid = threadIdx.x;
    for (int i=tid;i<2048;i+=256) sW1[i] = W1[i];
    for (int i=tid;i<8192;i+=256) sW2[i] = W2[i];
    for (int i=tid;i<512;i+=256)  sW3[i] = W3[i];
    if (tid<128){ float s = g1[tid]*rsqrtf(v1[tid]+1e-5f); sA1[tid]=s; sB1[tid]=(b1[tid]-m1[tid])*s+bt1[tid]; }
    if (tid<64){  float s = g2[tid]*rsqrtf(v2[tid]+1e-5f); sA2[tid]=s; sB2[tid]=(b2[tid]-m2[tid])*s+bt2[tid]; }
    if (tid<8)   sb3[tid] = b3[tid];
    __syncthreads();

    int row = blockIdx.x*256 + tid;
    const float4* xp = (const float4*)(x + row*16);
    float4 xv0 = xp[0], xv1 = xp[1], xv2 = xp[2], xv3 = xp[3];

    float h1[128];
    const float4* w1v = (const float4*)sW1;
    #pragma unroll 4
    for (int j=0;j<128;++j){
        float4 w0=w1v[j*4+0], w1=w1v[j*4+1], w2=w1v[j*4+2], w3=w1v[j*4+3];
        float a = xv0.x*w0.x + xv0.y*w0.y + xv0.z*w0.z + xv0.w*w0.w
                + xv1.x*w1.x + xv1.y*w1.y + xv1.z*w1.z + xv1.w*w1.w
                + xv2.x*w2.x + xv2.y*w2.y + xv2.z*w2.z + xv2.w*w2.w
                + xv3.x*w3.x + xv3.y*w3.y + xv3.z*w3.z + xv3.w*w3.w;
        h1[j] = fmaxf(fmaf(a, sA1[j], sB1[j]), 0.f);
    }
    float h2[64];
    const float4* w2v = (const float4*)sW2;
    #pragma unroll 2
    for (int j=0;j<64;++j){
        float a = 0.f;
        #pragma unroll
        for (int k=0;k<32;++k){
            float4 w = w2v[j*32+k];
            a = fmaf(h1[4*k+0], w.x, a);
            a = fmaf(h1[4*k+1], w.y, a);
            a = fmaf(h1[4*k+2], w.z, a);
            a = fmaf(h1[4*k+3], w.w, a);
        }
        h2[j] = fmaxf(fmaf(a, sA2[j], sB2[j]), 0.f);
    }
    float pr[8];
    const float4* w3v = (const float4*)sW3;
    #pragma unroll
    for (int j=0;j<8;++j){
        float a = sb3[j];
        #pragma unroll
        for (int k=0;k<16;++k){
            float4 w = w3v[j*16+k];
            a = fmaf(h2[4*k+0], w.x, a);
            a = fmaf(h2[4*k+1], w.y, a);
            a = fmaf(h2[4*k+2], w.z, a);
            a = fmaf(h2[4*k+3], w.w, a);
        }
        pr[j] = tanhf(a);
    }
    float4* po = (float4*)(pre + row*8);
    po[0] = make_float4(pr[0],pr[1],pr[2],pr[3]);
    po[1] = make_float4(pr[4],pr[5],pr[6],pr[7]);
}

// ---------- K5: fused s0-expand + MFMA GEMM + probs/Z + back MLP ----------
// Grid: 1024 wgs x 256 thr, 64 batch rows per wg.
// LDS layout: [0, 34304): A-tile (64 x 264 f16) then reused as probs (32 x 268 f32, per half)
//             [34304, 38400): qacc 4x32x8 f32;  [38400, 40448): qout 64x8 f32
#define A_STRIDE 264
#define P_STRIDE 268
__global__ __launch_bounds__(256,2) void k_main(
    const float* __restrict__ pre, const unsigned short* __restrict__ Wq,
    const float* __restrict__ W4, const float* __restrict__ b4, const float* __restrict__ g4,
    const float* __restrict__ bt4, const float* __restrict__ m4, const float* __restrict__ v4,
    const float* __restrict__ W5, const float* __restrict__ b5,
    const float* __restrict__ W6, const float* __restrict__ b6,
    float* __restrict__ out)
{
    __shared__ __align__(16) char smem[34304 + 4096 + 2048];
    unsigned short* As = (unsigned short*)smem;
    float* probs = (float*)smem;
    float* qacc  = (float*)(smem + 34304);
    float* qout  = (float*)(smem + 34304 + 4096);

    int tid = threadIdx.x;
    // -------- Phase 0: expand product state s0 into LDS A-tile (f16) --------
    // Reference einsum applies RY^T in the encoding too: |0> -> (cos, -sin),
    // so the bit=1 factor is -sin(theta/2): negate sn after sincos.
    {
        int row = tid & 63, q = tid >> 6;         // q = bits7..6 of amplitude index
        int grow = blockIdx.x*64 + row;
        const float4* p4 = (const float4*)(pre + grow*8);
        float4 pa = p4[0], pb = p4[1];
        float th[8] = {pa.x,pa.y,pa.z,pa.w,pb.x,pb.y,pb.z,pb.w};
        float cs[8], sn[8];
        #pragma unroll
        for (int i=0;i<8;++i){ sincosf(0.5f*th[i], &sn[i], &cs[i]); sn[i] = -sn[i]; }
        float F = (q&2 ? sn[0] : cs[0]) * (q&1 ? sn[1] : cs[1]);
        float Pm[8], Pl[8];
        #pragma unroll
        for (int a2=0;a2<8;++a2){
            Pm[a2] = (a2&4?sn[2]:cs[2]) * (a2&2?sn[3]:cs[3]) * (a2&1?sn[4]:cs[4]);
            Pl[a2] = (a2&4?sn[5]:cs[5]) * (a2&2?sn[6]:cs[6]) * (a2&1?sn[7]:cs[7]);
        }
        unsigned short* arow = As + row*A_STRIDE + q*64;
        #pragma unroll
        for (int mh=0;mh<8;++mh){
            float fm = F * Pm[mh];
            uint4 w;
            w.x = (unsigned)f2h(fm*Pl[0]) | ((unsigned)f2h(fm*Pl[1])<<16);
            w.y = (unsigned)f2h(fm*Pl[2]) | ((unsigned)f2h(fm*Pl[3])<<16);
            w.z = (unsigned)f2h(fm*Pl[4]) | ((unsigned)f2h(fm*Pl[5])<<16);
            w.w = (unsigned)f2h(fm*Pl[6]) | ((unsigned)f2h(fm*Pl[7])<<16);
            *reinterpret_cast<uint4*>(arow + mh*8) = w;
        }
    }
    __syncthreads();

    // -------- Phase 1: MFMA GEMM: C[64 x 512] = A[64 x 256] * W^T --------
    int wave = tid >> 6, lane = tid & 63;
    int l15 = lane & 15, lq = lane >> 4;

    const f16x8* Bp[8];
    #pragma unroll
    for (int t=0;t<8;++t){
        int n = wave*64 + (t&3)*16 + ((t>>2)<<8) + l15;   // tiles 0-3: Re, 4-7: Im (+256)
        Bp[t] = reinterpret_cast<const f16x8*>(Wq + n*256 + lq*8);
    }
    const f16x8* Ap[4];
    #pragma unroll
    for (int mt=0;mt<4;++mt)
        Ap[mt] = reinterpret_cast<const f16x8*>(As + (mt*16 + l15)*A_STRIDE + lq*8);

    f32x4 acc[4][8];
    const f32x4 zz = {0.f,0.f,0.f,0.f};
    #pragma unroll
    for (int mt=0;mt<4;++mt)
        #pragma unroll
        for (int t=0;t<8;++t) acc[mt][t] = zz;

    f16x8 bfr[2][8];
    #pragma unroll
    for (int t=0;t<8;++t) bfr[0][t] = Bp[t][0];

    #pragma unroll
    for (int ks=0;ks<8;++ks){
        int cur = ks & 1;
        if (ks < 7){
            #pragma unroll
            for (int t=0;t<8;++t) bfr[cur^1][t] = Bp[t][(ks+1)*4];  // +32 f16 per step
        }
        f16x8 afr[4];
        #pragma unroll
        for (int mt=0;mt<4;++mt) afr[mt] = Ap[mt][ks*4];
        #pragma unroll
        for (int mt=0;mt<4;++mt)
            #pragma unroll
            for (int t=0;t<8;++t)
                acc[mt][t] = __builtin_amdgcn_mfma_f32_16x16x32_f16(afr[mt], bfr[cur][t], acc[mt][t], 0, 0, 0);
    }
    __syncthreads();   // A-tile dead; LDS reused for probs

    // -------- Phase 2: probs -> <Z_i> -> back MLP --------
    #pragma unroll
    for (int h=0; h<2; ++h){
        #pragma unroll
        for (int mtl=0; mtl<2; ++mtl){
            int mt = h*2 + mtl;
            #pragma unroll
            for (int t=0;t<4;++t){
                #pragma unroll
                for (int reg=0;reg<4;++reg){
                    float sr = acc[mt][t][reg];
                    float si = acc[mt][t+4][reg];
                    int prow = mtl*16 + lq*4 + reg;           // local row 0..31
                    int pcol = wave*64 + t*16 + l15;          // amplitude index 0..255
                    probs[prow*P_STRIDE + pcol] = fmaf(sr,sr,si*si);
                }
            }
        }
        __syncthreads();
        if (tid < 128){
            int row = tid & 31, kg = tid >> 5;     // kg = bits7..6 of amplitude index
            const float* pb = probs + row*P_STRIDE + kg*64;
            float S=0.f,q2=0.f,q3=0.f,q4=0.f,q5=0.f,q6=0.f,q7=0.f;
            #pragma unroll
            for (int j=0;j<64;++j){
                float p = pb[j];
                S  += p;
                q2 += (j&32)? -p : p;   // qubit2 <-> bit5
                q3 += (j&16)? -p : p;
                q4 += (j&8) ? -p : p;
                q5 += (j&4) ? -p : p;
                q6 += (j&2) ? -p : p;
                q7 += (j&1) ? -p : p;
            }
            float* qa = qacc + tid*8;
            qa[0] = (kg&2)? -S : S;     // qubit0 <-> bit7
            qa[1] = (kg&1)? -S : S;     // qubit1 <-> bit6
            qa[2]=q2; qa[3]=q3; qa[4]=q4; qa[5]=q5; qa[6]=q6; qa[7]=q7;
        }
        __syncthreads();
        {   // combine 4 kg partials -> qout
            int r = tid >> 3, i = tid & 7;
            float v = qacc[r*8+i] + qacc[(32+r)*8+i] + qacc[(64+r)*8+i] + qacc[(96+r)*8+i];
            qout[(h*32 + r)*8 + i] = v;
        }
    }
    __syncthreads();

    if (tid < 64){
        int r = tid;
        float qv[8];
        #pragma unroll
        for (int i=0;i<8;++i) qv[i] = qout[r*8+i];
        float h4[32];
        #pragma unroll
        for (int j=0;j<32;++j){
            float a = b4[j];
            #pragma unroll
            for (int i=0;i<8;++i) a = fmaf(qv[i], W4[j*8+i], a);
            float sc = g4[j]*rsqrtf(v4[j]+1e-5f);
            a = fmaf(a - m4[j], sc, bt4[j]);
            h4[j] = fmaxf(a, 0.f);
        }
        float h5[16];
        #pragma unroll
        for (int j=0;j<16;++j){
            float a = b5[j];
            #pragma unroll
            for (int k=0;k<32;++k) a = fmaf(h4[k], W5[j*32+k], a);
            h5[j] = fmaxf(a, 0.f);
        }
        float o = b6[0];
        #pragma unroll
        for (int k=0;k<16;++k) o = fmaf(h5[k], W6[k], o);
        out[blockIdx.x*64 + r] = o;
    }
}

// ---------- launch ----------
extern "C" void kernel_launch(void* const* d_in, const int* in_sizes, int n_in,
                              void* d_out, int out_size, void* d_ws, size_t ws_size,
                              hipStream_t stream) {
    (void)in_sizes; (void)n_in; (void)out_size; (void)ws_size;
    const float* x   = (const float*)d_in[0];
    const float* W1  = (const float*)d_in[1];
    const float* b1  = (const float*)d_in[2];
    const float* g1  = (const float*)d_in[3];
    const float* bt1 = (const float*)d_in[4];
    const float* m1  = (const float*)d_in[5];
    const float* v1  = (const float*)d_in[6];
    const float* W2  = (const float*)d_in[7];
    const float* b2  = (const float*)d_in[8];
    const float* g2  = (const float*)d_in[9];
    const float* bt2 = (const float*)d_in[10];
    const float* m2  = (const float*)d_in[11];
    const float* v2  = (const float*)d_in[12];
    const float* W3  = (const float*)d_in[13];
    const float* b3  = (const float*)d_in[14];
    const float* qw  = (const float*)d_in[15];
    const float* W4  = (const float*)d_in[16];
    const float* b4  = (const float*)d_in[17];
    const float* g4  = (const float*)d_in[18];
    const float* bt4 = (const float*)d_in[19];
    const float* m4  = (const float*)d_in[20];
    const float* v4  = (const float*)d_in[21];
    const float* W5  = (const float*)d_in[22];
    const float* b5  = (const float*)d_in[23];
    const float* W6  = (const float*)d_in[24];
    const float* b6  = (const float*)d_in[25];

    char* ws = (char*)d_ws;
    float2* U   = (float2*)ws;                       // 3 * 65536 float2  (1.5 MB)
    float2* U21 = U + 3*65536;                       // 65536 float2      (0.5 MB)
    unsigned short* Wq = (unsigned short*)(U21 + 65536);  // 512*256 f16 (0.25 MB)
    float* pre  = (float*)(Wq + 512*256);            // 65536*8 f32       (2 MB)

    k_build_layers<<<dim3(256,3), 256, 0, stream>>>(qw, U);
    k_cmm<<<128, 256, 0, stream>>>(U + 65536, U, U21);          // U21 = U2*U1
    k_cmm_f16<<<128, 256, 0, stream>>>(U + 2*65536, U21, Wq);   // W = [Re;Im](U3*U21)
    k_mlp_front<<<256, 256, 0, stream>>>(x, W1,b1,g1,bt1,m1,v1,
                                         W2,b2,g2,bt2,m2,v2, W3,b3, pre);
    k_main<<<1024, 256, 0, stream>>>(pre, Wq, W4,b4,g4,bt4,m4,v4, W5,b5,W6,b6,
                                     (float*)d_out);
}

// Round 4
// 277.749 us; speedup vs baseline: 1.0138x; 1.0138x over previous
//
#include <hip/hip_runtime.h>

// ---------- helpers ----------
__device__ __forceinline__ float2 cmul(float2 a, float2 b){
    return make_float2(a.x*b.x - a.y*b.y, a.x*b.y + a.y*b.x);
}
__device__ __forceinline__ float2 cadd(float2 a, float2 b){
    return make_float2(a.x + b.x, a.y + b.y);
}
__device__ __forceinline__ unsigned short f2h(float f){
    _Float16 h = (_Float16)f;                    // v_cvt_f16_f32, round-nearest
    return __builtin_bit_cast(unsigned short, h);
}

typedef _Float16 f16x8 __attribute__((ext_vector_type(8)));
typedef float    f32x4 __attribute__((ext_vector_type(4)));

// Effective per-qubit operator (reference einsum applies U^T):
// G = RZ * RY(-t) * RX ; builds into Gd[8][2][2].
__device__ __forceinline__ void build_gates(const float* qw, int l, int c, float2 (*G)[2][2]){
    if (c < 8){
        int i = c;
        float t0 = 0.5f*qw[l*24 + i*3 + 0];
        float t1 = 0.5f*qw[l*24 + i*3 + 1];
        float t2 = 0.5f*qw[l*24 + i*3 + 2];
        float c1,s1,c2,s2,c3,s3;
        sincosf(t0,&s1,&c1); sincosf(t1,&s2,&c2); sincosf(t2,&s3,&c3);
        float2 RX[2][2] = {{{c1,0.f},{0.f,-s1}},{{0.f,-s1},{c1,0.f}}};
        // RY^T (transposed: sine sign flipped)
        float2 RY[2][2] = {{{c2,0.f},{s2,0.f}},{{-s2,0.f},{c2,0.f}}};
        float2 M[2][2];
        #pragma unroll
        for (int r=0;r<2;++r)
            #pragma unroll
            for (int cc=0;cc<2;++cc)
                M[r][cc] = cadd(cmul(RY[r][0],RX[0][cc]), cmul(RY[r][1],RX[1][cc]));
        float2 e  = {c3,-s3};
        float2 ec = {c3, s3};
        G[i][0][0]=cmul(e, M[0][0]); G[i][0][1]=cmul(e, M[0][1]);
        G[i][1][0]=cmul(ec,M[1][0]); G[i][1][1]=cmul(ec,M[1][1]);
    }
}
__device__ __forceinline__ int cnot_perm(int k){
    // apply CNOT list in reverse order (each is an involution)
    int r = k;
    for (int i=6;i>=0;--i)
        for (int j=7;j>i;--j)
            if ((r >> (7-i)) & 1) r ^= 1 << (7-j);
    return r;
}

// ---------- K1: build layer-0/1 256x256 operators ----------
// U_l[k][c] = T[P(k)][c],  T = G7 (x) ... (x) G0, qubit i on bit (7-i).
__global__ void k_build_layers(const float* __restrict__ qw, float2* __restrict__ U){
    __shared__ float2 G[8][2][2];
    int l = blockIdx.y, k = blockIdx.x, c = threadIdx.x;
    build_gates(qw, l, c, G);
    __syncthreads();
    int r = cnot_perm(k);
    float2 p = {1.f, 0.f};
    #pragma unroll
    for (int i=0;i<8;++i)
        p = cmul(p, G[i][(r>>(7-i))&1][(c>>(7-i))&1]);
    U[l*65536 + k*256 + c] = p;
}

// ---------- K2: per-row W = row_r(U3*U2*U1) -> fp16 [Re; Im] (512x256) ----------
// v = e_r U3 (built from layer-2 gates directly), w = v U2, z = w U1.
__global__ __launch_bounds__(256) void k_rowmm(const float* __restrict__ qw,
                                              const float2* __restrict__ U,
                                              unsigned short* __restrict__ W){
    __shared__ float2 G[8][2][2];
    __shared__ float2 vs[256];
    __shared__ float2 ws[256];
    int r = blockIdx.x, c = threadIdx.x;
    build_gates(qw, 2, c, G);
    __syncthreads();
    int pr = cnot_perm(r);
    float2 p = {1.f, 0.f};
    #pragma unroll
    for (int i=0;i<8;++i)
        p = cmul(p, G[i][(pr>>(7-i))&1][(c>>(7-i))&1]);
    vs[c] = p;
    __syncthreads();
    float2 acc = {0.f,0.f};
    #pragma unroll 8
    for (int m=0;m<256;++m)
        acc = cadd(acc, cmul(vs[m], U[65536 + m*256 + c]));   // U2
    ws[c] = acc;
    __syncthreads();
    float2 z = {0.f,0.f};
    #pragma unroll 8
    for (int m=0;m<256;++m)
        z = cadd(z, cmul(ws[m], U[m*256 + c]));               // U1
    W[r*256 + c]       = f2h(z.x);
    W[(r+256)*256 + c] = f2h(z.y);
}

// ---------- K3: fp32 front MLP: x -> pre (65536 x 8) ----------
// h1 computed in 16-wide chunks accumulated into h2a[64] -> no 128-reg live
// array, no scratch spill (R3 fix: WRITE_SIZE was 51 MB vs 2 MB ideal).
__global__ __launch_bounds__(256) void k_mlp_front(
    const float* __restrict__ x,
    const float* __restrict__ W1, const float* __restrict__ b1, const float* __restrict__ g1,
    const float* __restrict__ bt1, const float* __restrict__ m1, const float* __restrict__ v1,
    const float* __restrict__ W2, const float* __restrict__ b2, const float* __restrict__ g2,
    const float* __restrict__ bt2, const float* __restrict__ m2, const float* __restrict__ v2,
    const float* __restrict__ W3, const float* __restrict__ b3,
    float* __restrict__ pre)
{
    __shared__ float sW1[128*16];
    __shared__ float sA1[128], sB1[128];
    __shared__ float sW2[64*128];
    __shared__ float sA2[64], sB2[64];
    __shared__ float sW3[8*64];
    __shared__ float sb3[8];
    int tid = threadIdx.x;
    for (int i=tid;i<2048;i+=256) sW1[i] = W1[i];
    for (int i=tid;i<8192;i+=256) sW2[i] = W2[i];
    for (int i=tid;i<512;i+=256)  sW3[i] = W3[i];
    if (tid<128){ float s = g1[tid]*rsqrtf(v1[tid]+1e-5f); sA1[tid]=s; sB1[tid]=(b1[tid]-m1[tid])*s+bt1[tid]; }
    if (tid<64){  float s = g2[tid]*rsqrtf(v2[tid]+1e-5f); sA2[tid]=s; sB2[tid]=(b2[tid]-m2[tid])*s+bt2[tid]; }
    if (tid<8)   sb3[tid] = b3[tid];
    __syncthreads();

    int row = blockIdx.x*256 + tid;
    const float4* xp = (const float4*)(x + row*16);
    float4 xv0 = xp[0], xv1 = xp[1], xv2 = xp[2], xv3 = xp[3];

    const float4* w1v = (const float4*)sW1;
    const float4* w2v = (const float4*)sW2;

    float h2a[64];
    #pragma unroll
    for (int j=0;j<64;++j) h2a[j] = 0.f;

    #pragma unroll
    for (int ch=0; ch<8; ++ch){
        float h1c[16];
        #pragma unroll
        for (int jj=0;jj<16;++jj){
            int j = ch*16 + jj;
            float4 w0=w1v[j*4+0], w1=w1v[j*4+1], w2=w1v[j*4+2], w3=w1v[j*4+3];
            float a = xv0.x*w0.x + xv0.y*w0.y + xv0.z*w0.z + xv0.w*w0.w
                    + xv1.x*w1.x + xv1.y*w1.y + xv1.z*w1.z + xv1.w*w1.w
                    + xv2.x*w2.x + xv2.y*w2.y + xv2.z*w2.z + xv2.w*w2.w
                    + xv3.x*w3.x + xv3.y*w3.y + xv3.z*w3.z + xv3.w*w3.w;
            h1c[jj] = fmaxf(fmaf(a, sA1[j], sB1[j]), 0.f);
        }
        #pragma unroll 8
        for (int j=0;j<64;++j){
            float a = 0.f;
            #pragma unroll
            for (int k=0;k<4;++k){
                float4 w = w2v[j*32 + ch*4 + k];
                a = fmaf(h1c[k*4+0], w.x, a);
                a = fmaf(h1c[k*4+1], w.y, a);
                a = fmaf(h1c[k*4+2], w.z, a);
                a = fmaf(h1c[k*4+3], w.w, a);
            }
            h2a[j] += a;
        }
    }
    #pragma unroll
    for (int j=0;j<64;++j)
        h2a[j] = fmaxf(fmaf(h2a[j], sA2[j], sB2[j]), 0.f);

    float pr[8];
    const float4* w3v = (const float4*)sW3;
    #pragma unroll
    for (int j=0;j<8;++j){
        float a = sb3[j];
        #pragma unroll
        for (int k=0;k<16;++k){
            float4 w = w3v[j*16+k];
            a = fmaf(h2a[4*k+0], w.x, a);
            a = fmaf(h2a[4*k+1], w.y, a);
            a = fmaf(h2a[4*k+2], w.z, a);
            a = fmaf(h2a[4*k+3], w.w, a);
        }
        pr[j] = tanhf(a);
    }
    float4* po = (float4*)(pre + row*8);
    po[0] = make_float4(pr[0],pr[1],pr[2],pr[3]);
    po[1] = make_float4(pr[4],pr[5],pr[6],pr[7]);
}

// ---------- K4: fused s0-expand + MFMA GEMM + probs/Z + back MLP ----------
// Grid: 1024 wgs x 256 thr, 64 batch rows per wg.
// LDS layout: [0, 34304): A-tile (64 x 264 f16) then reused as probs (32 x 268 f32, per half)
//             [34304, 38400): qacc 4x32x8 f32;  [38400, 40448): qout 64x8 f32
#define A_STRIDE 264
#define P_STRIDE 268
__global__ __launch_bounds__(256,2) void k_main(
    const float* __restrict__ pre, const unsigned short* __restrict__ Wq,
    const float* __restrict__ W4, const float* __restrict__ b4, const float* __restrict__ g4,
    const float* __restrict__ bt4, const float* __restrict__ m4, const float* __restrict__ v4,
    const float* __restrict__ W5, const float* __restrict__ b5,
    const float* __restrict__ W6, const float* __restrict__ b6,
    float* __restrict__ out)
{
    __shared__ __align__(16) char smem[34304 + 4096 + 2048];
    unsigned short* As = (unsigned short*)smem;
    float* probs = (float*)smem;
    float* qacc  = (float*)(smem + 34304);
    float* qout  = (float*)(smem + 34304 + 4096);

    int tid = threadIdx.x;
    // -------- Phase 0: expand product state s0 into LDS A-tile (f16) --------
    // Encoding applies RY^T: |0> -> (cos, -sin) => bit=1 factor is -sin.
    {
        int row = tid & 63, q = tid >> 6;         // q = bits7..6 of amplitude index
        int grow = blockIdx.x*64 + row;
        const float4* p4 = (const float4*)(pre + grow*8);
        float4 pa = p4[0], pb = p4[1];
        float th[8] = {pa.x,pa.y,pa.z,pa.w,pb.x,pb.y,pb.z,pb.w};
        float cs[8], sn[8];
        #pragma unroll
        for (int i=0;i<8;++i){ __sincosf(0.5f*th[i], &sn[i], &cs[i]); sn[i] = -sn[i]; }
        float F = (q&2 ? sn[0] : cs[0]) * (q&1 ? sn[1] : cs[1]);
        float Pm[8], Pl[8];
        #pragma unroll
        for (int a2=0;a2<8;++a2){
            Pm[a2] = (a2&4?sn[2]:cs[2]) * (a2&2?sn[3]:cs[3]) * (a2&1?sn[4]:cs[4]);
            Pl[a2] = (a2&4?sn[5]:cs[5]) * (a2&2?sn[6]:cs[6]) * (a2&1?sn[7]:cs[7]);
        }
        unsigned short* arow = As + row*A_STRIDE + q*64;
        #pragma unroll
        for (int mh=0;mh<8;++mh){
            float fm = F * Pm[mh];
            uint4 w;
            w.x = (unsigned)f2h(fm*Pl[0]) | ((unsigned)f2h(fm*Pl[1])<<16);
            w.y = (unsigned)f2h(fm*Pl[2]) | ((unsigned)f2h(fm*Pl[3])<<16);
            w.z = (unsigned)f2h(fm*Pl[4]) | ((unsigned)f2h(fm*Pl[5])<<16);
            w.w = (unsigned)f2h(fm*Pl[6]) | ((unsigned)f2h(fm*Pl[7])<<16);
            *reinterpret_cast<uint4*>(arow + mh*8) = w;
        }
    }
    __syncthreads();

    // -------- Phase 1: MFMA GEMM: C[64 x 512] = A[64 x 256] * W^T --------
    int wave = tid >> 6, lane = tid & 63;
    int l15 = lane & 15, lq = lane >> 4;

    const f16x8* Bp[8];
    #pragma unroll
    for (int t=0;t<8;++t){
        int n = wave*64 + (t&3)*16 + ((t>>2)<<8) + l15;   // tiles 0-3: Re, 4-7: Im (+256)
        Bp[t] = reinterpret_cast<const f16x8*>(Wq + n*256 + lq*8);
    }
    const f16x8* Ap[4];
    #pragma unroll
    for (int mt=0;mt<4;++mt)
        Ap[mt] = reinterpret_cast<const f16x8*>(As + (mt*16 + l15)*A_STRIDE + lq*8);

    f32x4 acc[4][8];
    const f32x4 zz = {0.f,0.f,0.f,0.f};
    #pragma unroll
    for (int mt=0;mt<4;++mt)
        #pragma unroll
        for (int t=0;t<8;++t) acc[mt][t] = zz;

    f16x8 bfr[2][8];
    #pragma unroll
    for (int t=0;t<8;++t) bfr[0][t] = Bp[t][0];

    #pragma unroll
    for (int ks=0;ks<8;++ks){
        int cur = ks & 1;
        if (ks < 7){
            #pragma unroll
            for (int t=0;t<8;++t) bfr[cur^1][t] = Bp[t][(ks+1)*4];  // +32 f16 per step
        }
        f16x8 afr[4];
        #pragma unroll
        for (int mt=0;mt<4;++mt) afr[mt] = Ap[mt][ks*4];
        #pragma unroll
        for (int mt=0;mt<4;++mt)
            #pragma unroll
            for (int t=0;t<8;++t)
                acc[mt][t] = __builtin_amdgcn_mfma_f32_16x16x32_f16(afr[mt], bfr[cur][t], acc[mt][t], 0, 0, 0);
    }
    __syncthreads();   // A-tile dead; LDS reused for probs

    // -------- Phase 2: probs -> <Z_i> -> back MLP --------
    #pragma unroll
    for (int h=0; h<2; ++h){
        #pragma unroll
        for (int mtl=0; mtl<2; ++mtl){
            int mt = h*2 + mtl;
            #pragma unroll
            for (int t=0;t<4;++t){
                #pragma unroll
                for (int reg=0;reg<4;++reg){
                    float sr = acc[mt][t][reg];
                    float si = acc[mt][t+4][reg];
                    int prow = mtl*16 + lq*4 + reg;           // local row 0..31
                    int pcol = wave*64 + t*16 + l15;          // amplitude index 0..255
                    probs[prow*P_STRIDE + pcol] = fmaf(sr,sr,si*si);
                }
            }
        }
        __syncthreads();
        if (tid < 128){
            int row = tid & 31, kg = tid >> 5;     // kg = bits7..6 of amplitude index
            const float* pb = probs + row*P_STRIDE + kg*64;
            float S=0.f,q2=0.f,q3=0.f,q4=0.f,q5=0.f,q6=0.f,q7=0.f;
            #pragma unroll
            for (int j=0;j<64;++j){
                float p = pb[j];
                S  += p;
                q2 += (j&32)? -p : p;   // qubit2 <-> bit5
                q3 += (j&16)? -p : p;
                q4 += (j&8) ? -p : p;
                q5 += (j&4) ? -p : p;
                q6 += (j&2) ? -p : p;
                q7 += (j&1) ? -p : p;
            }
            float* qa = qacc + tid*8;
            qa[0] = (kg&2)? -S : S;     // qubit0 <-> bit7
            qa[1] = (kg&1)? -S : S;     // qubit1 <-> bit6
            qa[2]=q2; qa[3]=q3; qa[4]=q4; qa[5]=q5; qa[6]=q6; qa[7]=q7;
        }
        __syncthreads();
        {   // combine 4 kg partials -> qout
            int r = tid >> 3, i = tid & 7;
            float v = qacc[r*8+i] + qacc[(32+r)*8+i] + qacc[(64+r)*8+i] + qacc[(96+r)*8+i];
            qout[(h*32 + r)*8 + i] = v;
        }
    }
    __syncthreads();

    if (tid < 64){
        int r = tid;
        float qv[8];
        #pragma unroll
        for (int i=0;i<8;++i) qv[i] = qout[r*8+i];
        float h4[32];
        #pragma unroll
        for (int j=0;j<32;++j){
            float a = b4[j];
            #pragma unroll
            for (int i=0;i<8;++i) a = fmaf(qv[i], W4[j*8+i], a);
            float sc = g4[j]*rsqrtf(v4[j]+1e-5f);
            a = fmaf(a - m4[j], sc, bt4[j]);
            h4[j] = fmaxf(a, 0.f);
        }
        float h5[16];
        #pragma unroll
        for (int j=0;j<16;++j){
            float a = b5[j];
            #pragma unroll
            for (int k=0;k<32;++k) a = fmaf(h4[k], W5[j*32+k], a);
            h5[j] = fmaxf(a, 0.f);
        }
        float o = b6[0];
        #pragma unroll
        for (int k=0;k<16;++k) o = fmaf(h5[k], W6[k], o);
        out[blockIdx.x*64 + r] = o;
    }
}

// ---------- launch ----------
extern "C" void kernel_launch(void* const* d_in, const int* in_sizes, int n_in,
                              void* d_out, int out_size, void* d_ws, size_t ws_size,
                              hipStream_t stream) {
    (void)in_sizes; (void)n_in; (void)out_size; (void)ws_size;
    const float* x   = (const float*)d_in[0];
    const float* W1  = (const float*)d_in[1];
    const float* b1  = (const float*)d_in[2];
    const float* g1  = (const float*)d_in[3];
    const float* bt1 = (const float*)d_in[4];
    const float* m1  = (const float*)d_in[5];
    const float* v1  = (const float*)d_in[6];
    const float* W2  = (const float*)d_in[7];
    const float* b2  = (const float*)d_in[8];
    const float* g2  = (const float*)d_in[9];
    const float* bt2 = (const float*)d_in[10];
    const float* m2  = (const float*)d_in[11];
    const float* v2  = (const float*)d_in[12];
    const float* W3  = (const float*)d_in[13];
    const float* b3  = (const float*)d_in[14];
    const float* qw  = (const float*)d_in[15];
    const float* W4  = (const float*)d_in[16];
    const float* b4  = (const float*)d_in[17];
    const float* g4  = (const float*)d_in[18];
    const float* bt4 = (const float*)d_in[19];
    const float* m4  = (const float*)d_in[20];
    const float* v4  = (const float*)d_in[21];
    const float* W5  = (const float*)d_in[22];
    const float* b5  = (const float*)d_in[23];
    const float* W6  = (const float*)d_in[24];
    const float* b6  = (const float*)d_in[25];

    char* ws = (char*)d_ws;
    float2* U   = (float2*)ws;                       // 2 * 65536 float2  (1 MB)
    unsigned short* Wq = (unsigned short*)(U + 2*65536);  // 512*256 f16 (0.25 MB)
    float* pre  = (float*)(Wq + 512*256);            // 65536*8 f32       (2 MB)

    k_build_layers<<<dim3(256,2), 256, 0, stream>>>(qw, U);      // U1, U2
    k_rowmm<<<256, 256, 0, stream>>>(qw, U, Wq);                 // W = [Re;Im](U3*U2*U1)
    k_mlp_front<<<256, 256, 0, stream>>>(x, W1,b1,g1,bt1,m1,v1,
                                         W2,b2,g2,bt2,m2,v2, W3,b3, pre);
    k_main<<<1024, 256, 0, stream>>>(pre, Wq, W4,b4,g4,bt4,m4,v4, W5,b5,W6,b6,
                                     (float*)d_out);
}